// Round 1
// baseline (117.369 us; speedup 1.0000x reference)
//
#include <hip/hip_runtime.h>
#include <hip/hip_bf16.h>

#define B_ 8
#define T_ 2048
#define C_ 768
#define H_ 64
#define BT_ (B_*T_)

typedef __attribute__((ext_vector_type(8))) short bf16x8;
typedef __attribute__((ext_vector_type(4))) float f32x4;

__device__ __forceinline__ unsigned short f2bf(float x) {
    __hip_bfloat16 h = __float2bfloat16(x);   // RNE
    return __builtin_bit_cast(unsigned short, h);
}

__device__ __forceinline__ bf16x8 cvt8(float4 a, float4 b) {
    bf16x8 r;
    r[0] = (short)f2bf(a.x); r[1] = (short)f2bf(a.y);
    r[2] = (short)f2bf(a.z); r[3] = (short)f2bf(a.w);
    r[4] = (short)f2bf(b.x); r[5] = (short)f2bf(b.y);
    r[6] = (short)f2bf(b.z); r[7] = (short)f2bf(b.w);
    return r;
}

// ------------- W prep (coalesced): block = (m, gc); LDS transpose ---------------
__global__ __launch_bounds__(256) void wprep(
    const float* __restrict__ Wq, const float* __restrict__ Wk,
    const float* __restrict__ Wv, unsigned short* __restrict__ WTf)
{
    __shared__ float tile[32][68];
    const int bid = blockIdx.x;              // 72 = 3 m * 24 gc
    const int m = bid / 24, gc = bid % 24;
    const float* __restrict__ W = (m == 0) ? Wq : (m == 1) ? Wk : Wv;
    const int t = threadIdx.x;
    {
        const int r = t >> 3, c0 = (t & 7) * 8;
        float4 a = *(const float4*)(W + (size_t)(gc * 32 + r) * H_ + c0);
        float4 b = *(const float4*)(W + (size_t)(gc * 32 + r) * H_ + c0 + 4);
        *(float4*)&tile[r][c0]     = a;
        *(float4*)&tile[r][c0 + 4] = b;
    }
    __syncthreads();
    const int fl = t >> 6, lane = t & 63;
    const int q16 = lane & 15, quad = lane >> 4;
    const int f = m * 4 + fl;
    ushort4 u0, u1;
    u0.x = f2bf(tile[quad * 8 + 0][fl * 16 + q16]);
    u0.y = f2bf(tile[quad * 8 + 1][fl * 16 + q16]);
    u0.z = f2bf(tile[quad * 8 + 2][fl * 16 + q16]);
    u0.w = f2bf(tile[quad * 8 + 3][fl * 16 + q16]);
    u1.x = f2bf(tile[quad * 8 + 4][fl * 16 + q16]);
    u1.y = f2bf(tile[quad * 8 + 5][fl * 16 + q16]);
    u1.z = f2bf(tile[quad * 8 + 6][fl * 16 + q16]);
    u1.w = f2bf(tile[quad * 8 + 7][fl * 16 + q16]);
    unsigned short* __restrict__ dst = WTf + ((size_t)(gc * 12 + f) * 64 + lane) * 8;
    *(ushort4*)(dst)     = u0;
    *(ushort4*)(dst + 4) = u1;
}

// ------------- QKV via MFMA: 16 tokens/block, intra-block N-split, NO merge -----
// R14 config (best measured together with R13: 118.1-118.6 us total; R15's
// 32-token variant regressed to 121.6 via occupancy loss). x staged once to
// LDS; wave w computes f-set w*3..w*3+2 over all 24 chunks; one barrier; all
// waves run the frag-packed epilogue in parallel. 24.7 KB LDS -> 6 blocks/CU.
__global__ __launch_bounds__(256) void qkv_kernel(
    const float* __restrict__ x, const unsigned short* __restrict__ WTf,
    unsigned short* __restrict__ qF, unsigned short* __restrict__ kF,
    unsigned short* __restrict__ vF)
{
    __shared__ __align__(16) unsigned short xS[16 * 772];   // 24.7 KB, padded rows
    const int tid  = threadIdx.x;
    const int w    = tid >> 6;               // f-set 0..3
    const int lane = tid & 63;
    const int q16  = lane & 15, quad = lane >> 4;
    const int rowBase = blockIdx.x << 4;

    // ---- stage x: thread t = (row t>>4, l=t&15); 6 x 32B contiguous per thread
    {
        const int r = tid >> 4, l = tid & 15;
        const float* __restrict__ xrow = x + (size_t)(rowBase + r) * C_;
        #pragma unroll
        for (int i = 0; i < 6; i++) {
            const int j = i * 16 + l;        // 32B granule 0..95
            float4 a = *(const float4*)(xrow + j * 8);
            float4 b = *(const float4*)(xrow + j * 8 + 4);
            *(bf16x8*)&xS[(size_t)r * 772 + j * 8] = cvt8(a, b);
        }
    }
    __syncthreads();                          // the only barrier

    const int f0 = w * 3;
    const unsigned short* __restrict__ xrowS = xS + q16 * 772 + quad * 8;
    f32x4 acc[3] = {};
    #pragma unroll
    for (int c = 0; c < 24; c++) {
        const unsigned short* __restrict__ wpc =
            WTf + ((size_t)(c * 12 + f0)) * 512 + lane * 8;
        bf16x8 xf = *(const bf16x8*)(xrowS + c * 32);   // ds_read_b128, <=2-way
        bf16x8 w0 = *(const bf16x8*)(wpc);
        bf16x8 w1 = *(const bf16x8*)(wpc + 512);
        bf16x8 w2 = *(const bf16x8*)(wpc + 1024);
        acc[0] = __builtin_amdgcn_mfma_f32_16x16x32_bf16(w0, xf, acc[0], 0, 0, 0);
        acc[1] = __builtin_amdgcn_mfma_f32_16x16x32_bf16(w1, xf, acc[1], 0, 0, 0);
        acc[2] = __builtin_amdgcn_mfma_f32_16x16x32_bf16(w2, xf, acc[2], 0, 0, 0);
    }

    // ---- fragment-packed epilogue (R11 mapping), run by ALL waves in parallel
    const size_t gt = (size_t)(rowBase >> 4);
    #pragma unroll
    for (int j = 0; j < 3; j++) {
        const int f = f0 + j;                // wave-uniform
        if (f < 8) {
            ushort4 u;
            u.x = f2bf(acc[j][0]); u.y = f2bf(acc[j][1]);
            u.z = f2bf(acc[j][2]); u.w = f2bf(acc[j][3]);
            const int n4 = f & 3;
            const int qp = (2 * n4 + (quad >> 1)) & 3;
            const int j0 = (quad & 1) * 4;
            unsigned short* __restrict__ dst = (f < 4) ? qF : kF;
            *(ushort4*)(dst + ((gt * 2 + (n4 >> 1)) * 64 + q16 + 16 * qp) * 8 + j0) = u;
        } else {
            const size_t g32 = gt >> 1;
            const int qv = ((int)gt & 1) * 2 + (q16 >> 3);
            const int jv = q16 & 7;
            #pragma unroll
            for (int r = 0; r < 4; r++)
                vF[((g32 * 4 + (f - 8)) * 64 + quad * 4 + r + 16 * qv) * 8 + jv] =
                    f2bf(acc[j][r]);
        }
    }
}

// ------------- MFMA flash attention: 4-wave k-split, no-max softmax -------------
// R16 changes vs the 115.4us version:
//  (1) balanced CU mapping: co-resident qt sets {127-r, 64+r, 63-r, r} sum to a
//      constant 66 wave-iters per CU (old heavy-first map ranged 80..49 -> the
//      makespan was the 80). Batch b stays in bid&7 so batch<->XCD L2 affinity
//      is preserved.
//  (2) causal mask only on the diagonal k-tile: for kt <= niter-2,
//      kidx_max = 64*niter-65 <= 16*qt <= qrow always (niter = ceil((qt+1)/4)
//      <= qt/4+1), so interior tiles skip the kidx compare/select entirely
//      (~2-3 VALU x 16 elems per iter). Branch is wave-uniform.
//  (3) psum as a balanced tree instead of a 16-deep serial add chain.
__global__ __launch_bounds__(256) void attn_kernel(
    const unsigned short* __restrict__ qF, const unsigned short* __restrict__ kF,
    const unsigned short* __restrict__ vF, const float* __restrict__ mask,
    float* __restrict__ out)
{
    __shared__ __align__(16) unsigned short pS[4][16][88];  // wave-private P tiles
    __shared__ float oS[3][64][17];          // o[16] + l in slot 16; stride 17 odd

    const int tid  = threadIdx.x;
    const int w    = tid >> 6;
    const int lane = tid & 63;
    const int q16  = lane & 15;
    const int quad = lane >> 4;
    const int bid  = blockIdx.x;
    const int b    = bid & 7;                    // batches interleaved (XCD affinity)
    const int g    = bid >> 3;
    const int r_   = g & 31, qd = g >> 5;
    const int qt   = (qd == 0) ? (127 - r_)      // balanced quadrant map:
                   : (qd == 1) ? (64 + r_)       // any co-resident {r_, r_+32, r_+64,
                   : (qd == 2) ? (63 - r_)       //  r_+96} set sums to 66 wave-iters
                   : r_;
    const int qrow = (qt << 4) + q16;

    const size_t qbase = ((size_t)(b * 128 + qt) * 2) * 512 + lane * 8;
    bf16x8 qf0 = *(const bf16x8*)(qF + qbase);
    bf16x8 qf1 = *(const bf16x8*)(qF + qbase + 512);
    // fold 1/sqrt(64) and log2(e): softmax runs in base-2 domain
    const float maskv = mask[b * T_ + qrow] * 0.125f * 1.44269504f;

    f32x4 o[4] = {};
    float l_run = 0.f;

    const int niter = ((qt << 4) + 16 + 63) >> 6;   // 64-wide k tiles
    const int dt    = niter - 1;                    // diagonal tile index
    for (int kt = w; kt < niter; kt += 4) {
        const int kbase = kt << 6;

        // ---- K and V fragment loads: all contiguous 1KB (lane*16B)
        bf16x8 kf[8], vf[8];
        #pragma unroll
        for (int sub = 0; sub < 4; sub++) {
            const unsigned short* kp = kF + ((size_t)(b * 128 + kt * 4 + sub) * 2) * 512 + lane * 8;
            kf[2 * sub]     = *(const bf16x8*)(kp);
            kf[2 * sub + 1] = *(const bf16x8*)(kp + 512);
        }
        #pragma unroll
        for (int ht = 0; ht < 4; ht++) {
            const unsigned short* vp = vF + ((size_t)(b * 64 + kt * 2) * 4 + ht) * 512 + lane * 8;
            vf[2 * ht]     = *(const bf16x8*)(vp);
            vf[2 * ht + 1] = *(const bf16x8*)(vp + 4 * 512);
        }

        // ---- S^T = K.Q^T : D[k_local][q]
        f32x4 sa[4] = {};
        #pragma unroll
        for (int sub = 0; sub < 4; sub++) {
            sa[sub] = __builtin_amdgcn_mfma_f32_16x16x32_bf16(kf[2 * sub],     qf0, sa[sub], 0, 0, 0);
            sa[sub] = __builtin_amdgcn_mfma_f32_16x16x32_bf16(kf[2 * sub + 1], qf1, sa[sub], 0, 0, 0);
        }

        // ---- reference semantics + unnormalized softmax: p = exp2(s), -inf -> 0
        float p[16];
        if (kt != dt) {
            // interior tile: kidx <= qrow guaranteed, no causal compare needed
            #pragma unroll
            for (int e = 0; e < 16; e++) {
                float sv = sa[e >> 2][e & 3] * maskv;
                float pv = exp2f(sv);
                p[e] = (sv == 0.f) ? 0.f : pv;   // masked_fill(qK==0) semantics
            }
        } else {
            // diagonal tile: full causal + zero-mask path
            #pragma unroll
            for (int sub = 0; sub < 4; sub++)
                #pragma unroll
                for (int r = 0; r < 4; r++) {
                    int kidx = kbase + sub * 16 + quad * 4 + r;
                    float sv = sa[sub][r] * maskv;
                    sv = (sv == 0.f) ? -__builtin_inff() : sv;
                    sv = (kidx > qrow) ? -__builtin_inff() : sv;
                    p[sub * 4 + r] = exp2f(sv);
                }
        }
        float psum = (((p[0] + p[1]) + (p[2] + p[3])) + ((p[4] + p[5]) + (p[6] + p[7])))
                   + (((p[8] + p[9]) + (p[10] + p[11])) + ((p[12] + p[13]) + (p[14] + p[15])));
        psum += __shfl_xor(psum, 16);
        psum += __shfl_xor(psum, 32);
        l_run += psum;

        // ---- P^T -> wave-private LDS as P[q][k] bf16 (intra-wave: no barrier)
        #pragma unroll
        for (int sub = 0; sub < 4; sub++) {
            unsigned int lo = (unsigned int)f2bf(p[sub * 4 + 0]) | ((unsigned int)f2bf(p[sub * 4 + 1]) << 16);
            unsigned int hi = (unsigned int)f2bf(p[sub * 4 + 2]) | ((unsigned int)f2bf(p[sub * 4 + 3]) << 16);
            *(uint2*)&pS[w][q16][sub * 16 + quad * 4] = make_uint2(lo, hi);
        }
        bf16x8 pf0 = *(const bf16x8*)&pS[w][q16][quad * 8];
        bf16x8 pf1 = *(const bf16x8*)&pS[w][q16][32 + quad * 8];

        // ---- O^T += V^T.P^T
        #pragma unroll
        for (int ht = 0; ht < 4; ht++) {
            o[ht] = __builtin_amdgcn_mfma_f32_16x16x32_bf16(vf[2 * ht],     pf0, o[ht], 0, 0, 0);
            o[ht] = __builtin_amdgcn_mfma_f32_16x16x32_bf16(vf[2 * ht + 1], pf1, o[ht], 0, 0, 0);
        }
    }

    // ---- merge = pure sums (no max state)
    if (w > 0) {
        #pragma unroll
        for (int ht = 0; ht < 4; ht++)
            #pragma unroll
            for (int r = 0; r < 4; r++) oS[w - 1][lane][ht * 4 + r] = o[ht][r];
        oS[w - 1][lane][16] = l_run;
    }
    __syncthreads();
    if (w == 0) {
        #pragma unroll
        for (int j = 0; j < 3; j++) {
            #pragma unroll
            for (int ht = 0; ht < 4; ht++)
                #pragma unroll
                for (int r = 0; r < 4; r++) o[ht][r] += oS[j][lane][ht * 4 + r];
            l_run += oS[j][lane][16];
        }
        const float invl = (l_run > 0.f) ? (1.f / l_run) : 0.f;  // dead row -> 0
        #pragma unroll
        for (int ht = 0; ht < 4; ht++) {
            float4 ov = make_float4(o[ht][0] * invl, o[ht][1] * invl,
                                    o[ht][2] * invl, o[ht][3] * invl);
            *(float4*)(out + ((size_t)(b * T_) + qrow) * H_ + ht * 16 + quad * 4) = ov;
        }
    }
}

extern "C" void kernel_launch(void* const* d_in, const int* in_sizes, int n_in,
                              void* d_out, int out_size, void* d_ws, size_t ws_size,
                              hipStream_t stream) {
    const float* x    = (const float*)d_in[0];
    const float* mask = (const float*)d_in[1];
    const float* Wq   = (const float*)d_in[2];
    const float* Wk   = (const float*)d_in[3];
    const float* Wv   = (const float*)d_in[4];
    float* out = (float*)d_out;

    unsigned short* qf = (unsigned short*)d_ws;            // bf16 frag-packed [BT*H]
    unsigned short* kf = qf + (size_t)BT_ * H_;
    unsigned short* vf = kf + (size_t)BT_ * H_;
    unsigned short* wt = vf + (size_t)BT_ * H_;            // bf16 WTf[24][12][64][8]

    wprep<<<72, 256, 0, stream>>>(Wq, Wk, Wv, wt);
    qkv_kernel<<<BT_ / 16, 256, 0, stream>>>(x, wt, qf, kf, vf);
    attn_kernel<<<B_ * (T_ / 16), 256, 0, stream>>>(qf, kf, vf, mask, out);
}

// Round 2
// 115.726 us; speedup vs baseline: 1.0142x; 1.0142x over previous
//
#include <hip/hip_runtime.h>
#include <hip/hip_bf16.h>

#define B_ 8
#define T_ 2048
#define C_ 768
#define H_ 64
#define BT_ (B_*T_)

typedef __attribute__((ext_vector_type(8))) short bf16x8;
typedef __attribute__((ext_vector_type(4))) float f32x4;

__device__ __forceinline__ unsigned short f2bf(float x) {
    __hip_bfloat16 h = __float2bfloat16(x);   // RNE
    return __builtin_bit_cast(unsigned short, h);
}

__device__ __forceinline__ bf16x8 cvt8(float4 a, float4 b) {
    bf16x8 r;
    r[0] = (short)f2bf(a.x); r[1] = (short)f2bf(a.y);
    r[2] = (short)f2bf(a.z); r[3] = (short)f2bf(a.w);
    r[4] = (short)f2bf(b.x); r[5] = (short)f2bf(b.y);
    r[6] = (short)f2bf(b.z); r[7] = (short)f2bf(b.w);
    return r;
}

// ------------- W prep (coalesced): block = (m, gc); LDS transpose ---------------
__global__ __launch_bounds__(256) void wprep(
    const float* __restrict__ Wq, const float* __restrict__ Wk,
    const float* __restrict__ Wv, unsigned short* __restrict__ WTf)
{
    __shared__ float tile[32][68];
    const int bid = blockIdx.x;              // 72 = 3 m * 24 gc
    const int m = bid / 24, gc = bid % 24;
    const float* __restrict__ W = (m == 0) ? Wq : (m == 1) ? Wk : Wv;
    const int t = threadIdx.x;
    {
        const int r = t >> 3, c0 = (t & 7) * 8;
        float4 a = *(const float4*)(W + (size_t)(gc * 32 + r) * H_ + c0);
        float4 b = *(const float4*)(W + (size_t)(gc * 32 + r) * H_ + c0 + 4);
        *(float4*)&tile[r][c0]     = a;
        *(float4*)&tile[r][c0 + 4] = b;
    }
    __syncthreads();
    const int fl = t >> 6, lane = t & 63;
    const int q16 = lane & 15, quad = lane >> 4;
    const int f = m * 4 + fl;
    ushort4 u0, u1;
    u0.x = f2bf(tile[quad * 8 + 0][fl * 16 + q16]);
    u0.y = f2bf(tile[quad * 8 + 1][fl * 16 + q16]);
    u0.z = f2bf(tile[quad * 8 + 2][fl * 16 + q16]);
    u0.w = f2bf(tile[quad * 8 + 3][fl * 16 + q16]);
    u1.x = f2bf(tile[quad * 8 + 4][fl * 16 + q16]);
    u1.y = f2bf(tile[quad * 8 + 5][fl * 16 + q16]);
    u1.z = f2bf(tile[quad * 8 + 6][fl * 16 + q16]);
    u1.w = f2bf(tile[quad * 8 + 7][fl * 16 + q16]);
    unsigned short* __restrict__ dst = WTf + ((size_t)(gc * 12 + f) * 64 + lane) * 8;
    *(ushort4*)(dst)     = u0;
    *(ushort4*)(dst + 4) = u1;
}

// ------------- QKV via MFMA: 16 tokens/block, intra-block N-split, NO merge -----
// R14 config (best measured; untouched since — isolate the attn variable).
__global__ __launch_bounds__(256) void qkv_kernel(
    const float* __restrict__ x, const unsigned short* __restrict__ WTf,
    unsigned short* __restrict__ qF, unsigned short* __restrict__ kF,
    unsigned short* __restrict__ vF)
{
    __shared__ __align__(16) unsigned short xS[16 * 772];   // 24.7 KB, padded rows
    const int tid  = threadIdx.x;
    const int w    = tid >> 6;               // f-set 0..3
    const int lane = tid & 63;
    const int q16  = lane & 15, quad = lane >> 4;
    const int rowBase = blockIdx.x << 4;

    // ---- stage x: thread t = (row t>>4, l=t&15); 6 x 32B contiguous per thread
    {
        const int r = tid >> 4, l = tid & 15;
        const float* __restrict__ xrow = x + (size_t)(rowBase + r) * C_;
        #pragma unroll
        for (int i = 0; i < 6; i++) {
            const int j = i * 16 + l;        // 32B granule 0..95
            float4 a = *(const float4*)(xrow + j * 8);
            float4 b = *(const float4*)(xrow + j * 8 + 4);
            *(bf16x8*)&xS[(size_t)r * 772 + j * 8] = cvt8(a, b);
        }
    }
    __syncthreads();                          // the only barrier

    const int f0 = w * 3;
    const unsigned short* __restrict__ xrowS = xS + q16 * 772 + quad * 8;
    f32x4 acc[3] = {};
    #pragma unroll
    for (int c = 0; c < 24; c++) {
        const unsigned short* __restrict__ wpc =
            WTf + ((size_t)(c * 12 + f0)) * 512 + lane * 8;
        bf16x8 xf = *(const bf16x8*)(xrowS + c * 32);   // ds_read_b128, <=2-way
        bf16x8 w0 = *(const bf16x8*)(wpc);
        bf16x8 w1 = *(const bf16x8*)(wpc + 512);
        bf16x8 w2 = *(const bf16x8*)(wpc + 1024);
        acc[0] = __builtin_amdgcn_mfma_f32_16x16x32_bf16(w0, xf, acc[0], 0, 0, 0);
        acc[1] = __builtin_amdgcn_mfma_f32_16x16x32_bf16(w1, xf, acc[1], 0, 0, 0);
        acc[2] = __builtin_amdgcn_mfma_f32_16x16x32_bf16(w2, xf, acc[2], 0, 0, 0);
    }

    // ---- fragment-packed epilogue (R11 mapping), run by ALL waves in parallel
    const size_t gt = (size_t)(rowBase >> 4);
    #pragma unroll
    for (int j = 0; j < 3; j++) {
        const int f = f0 + j;                // wave-uniform
        if (f < 8) {
            ushort4 u;
            u.x = f2bf(acc[j][0]); u.y = f2bf(acc[j][1]);
            u.z = f2bf(acc[j][2]); u.w = f2bf(acc[j][3]);
            const int n4 = f & 3;
            const int qp = (2 * n4 + (quad >> 1)) & 3;
            const int j0 = (quad & 1) * 4;
            unsigned short* __restrict__ dst = (f < 4) ? qF : kF;
            *(ushort4*)(dst + ((gt * 2 + (n4 >> 1)) * 64 + q16 + 16 * qp) * 8 + j0) = u;
        } else {
            const size_t g32 = gt >> 1;
            const int qv = ((int)gt & 1) * 2 + (q16 >> 3);
            const int jv = q16 & 7;
            #pragma unroll
            for (int r = 0; r < 4; r++)
                vF[((g32 * 4 + (f - 8)) * 64 + quad * 4 + r + 16 * qv) * 8 + jv] =
                    f2bf(acc[j][r]);
        }
    }
}

// ------------- MFMA flash attention: 4-wave k-split, no-max softmax -------------
// R17:
//  (1) REVERT R16's quadrant map -> heavy-first qt = 127-(bid>>3). Blocks are
//      scheduled dynamically, so heavy-first IS the LPT schedule (R16's static
//      co-residency analysis was wrong; it measured +2.2us).
//  (2) KEEP diagonal-only causal masking (interior tiles provably satisfy
//      kidx <= qrow: niter = ceil((qt+1)/4) => 64*niter-65 <= 16*qt) and the
//      balanced-tree psum.
//  (3) NEW: rotated K/V loads. kf dies after QK^T, vf dies after PV, so the
//      loads for iteration kt+4 issue right after each consumer (zero VGPR
//      growth, WAR deps preserve order). K-latency hides under softmax+PV,
//      V-latency under a full iteration; only the prologue loads are exposed.
__global__ __launch_bounds__(256) void attn_kernel(
    const unsigned short* __restrict__ qF, const unsigned short* __restrict__ kF,
    const unsigned short* __restrict__ vF, const float* __restrict__ mask,
    float* __restrict__ out)
{
    __shared__ __align__(16) unsigned short pS[4][16][88];  // wave-private P tiles
    __shared__ float oS[3][64][17];          // o[16] + l in slot 16; stride 17 odd

    const int tid  = threadIdx.x;
    const int w    = tid >> 6;
    const int lane = tid & 63;
    const int q16  = lane & 15;
    const int quad = lane >> 4;
    const int bid  = blockIdx.x;
    const int b    = bid & 7;                    // batches interleaved (XCD affinity)
    const int qt   = 127 - (bid >> 3);           // heavy q-tiles first (LPT)
    const int qrow = (qt << 4) + q16;

    const size_t qbase = ((size_t)(b * 128 + qt) * 2) * 512 + lane * 8;
    bf16x8 qf0 = *(const bf16x8*)(qF + qbase);
    bf16x8 qf1 = *(const bf16x8*)(qF + qbase + 512);
    // fold 1/sqrt(64) and log2(e): softmax runs in base-2 domain
    const float maskv = mask[b * T_ + qrow] * 0.125f * 1.44269504f;

    f32x4 o[4] = {};
    float l_run = 0.f;

    const int niter = ((qt << 4) + 16 + 63) >> 6;   // 64-wide k tiles
    const int dt    = niter - 1;                    // diagonal tile index

    bf16x8 kf[8], vf[8];
    auto loadK = [&](int kt_) {
        #pragma unroll
        for (int sub = 0; sub < 4; sub++) {
            const unsigned short* kp = kF + ((size_t)(b * 128 + kt_ * 4 + sub) * 2) * 512 + lane * 8;
            kf[2 * sub]     = *(const bf16x8*)(kp);
            kf[2 * sub + 1] = *(const bf16x8*)(kp + 512);
        }
    };
    auto loadV = [&](int kt_) {
        #pragma unroll
        for (int ht = 0; ht < 4; ht++) {
            const unsigned short* vp = vF + ((size_t)(b * 64 + kt_ * 2) * 4 + ht) * 512 + lane * 8;
            vf[2 * ht]     = *(const bf16x8*)(vp);
            vf[2 * ht + 1] = *(const bf16x8*)(vp + 4 * 512);
        }
    };

    if (w < niter) { loadK(w); loadV(w); }       // prologue (wave-uniform guard)

    for (int kt = w; kt < niter; kt += 4) {
        const int kbase = kt << 6;
        const bool more = (kt + 4 < niter);      // wave-uniform

        // ---- S^T = K.Q^T : D[k_local][q]  (kf dies here)
        f32x4 sa[4] = {};
        #pragma unroll
        for (int sub = 0; sub < 4; sub++) {
            sa[sub] = __builtin_amdgcn_mfma_f32_16x16x32_bf16(kf[2 * sub],     qf0, sa[sub], 0, 0, 0);
            sa[sub] = __builtin_amdgcn_mfma_f32_16x16x32_bf16(kf[2 * sub + 1], qf1, sa[sub], 0, 0, 0);
        }
        if (more) loadK(kt + 4);                 // prefetch next K into dead kf

        // ---- reference semantics + unnormalized softmax: p = exp2(s), -inf -> 0
        float p[16];
        if (kt != dt) {
            // interior tile: kidx <= qrow guaranteed, no causal compare needed
            #pragma unroll
            for (int e = 0; e < 16; e++) {
                float sv = sa[e >> 2][e & 3] * maskv;
                float pv = exp2f(sv);
                p[e] = (sv == 0.f) ? 0.f : pv;   // masked_fill(qK==0) semantics
            }
        } else {
            // diagonal tile: full causal + zero-mask path
            #pragma unroll
            for (int sub = 0; sub < 4; sub++)
                #pragma unroll
                for (int r = 0; r < 4; r++) {
                    int kidx = kbase + sub * 16 + quad * 4 + r;
                    float sv = sa[sub][r] * maskv;
                    sv = (sv == 0.f) ? -__builtin_inff() : sv;
                    sv = (kidx > qrow) ? -__builtin_inff() : sv;
                    p[sub * 4 + r] = exp2f(sv);
                }
        }
        float psum = (((p[0] + p[1]) + (p[2] + p[3])) + ((p[4] + p[5]) + (p[6] + p[7])))
                   + (((p[8] + p[9]) + (p[10] + p[11])) + ((p[12] + p[13]) + (p[14] + p[15])));
        psum += __shfl_xor(psum, 16);
        psum += __shfl_xor(psum, 32);
        l_run += psum;

        // ---- P^T -> wave-private LDS as P[q][k] bf16 (intra-wave: no barrier)
        #pragma unroll
        for (int sub = 0; sub < 4; sub++) {
            unsigned int lo = (unsigned int)f2bf(p[sub * 4 + 0]) | ((unsigned int)f2bf(p[sub * 4 + 1]) << 16);
            unsigned int hi = (unsigned int)f2bf(p[sub * 4 + 2]) | ((unsigned int)f2bf(p[sub * 4 + 3]) << 16);
            *(uint2*)&pS[w][q16][sub * 16 + quad * 4] = make_uint2(lo, hi);
        }
        bf16x8 pf0 = *(const bf16x8*)&pS[w][q16][quad * 8];
        bf16x8 pf1 = *(const bf16x8*)&pS[w][q16][32 + quad * 8];

        // ---- O^T += V^T.P^T  (vf dies here)
        #pragma unroll
        for (int ht = 0; ht < 4; ht++) {
            o[ht] = __builtin_amdgcn_mfma_f32_16x16x32_bf16(vf[2 * ht],     pf0, o[ht], 0, 0, 0);
            o[ht] = __builtin_amdgcn_mfma_f32_16x16x32_bf16(vf[2 * ht + 1], pf1, o[ht], 0, 0, 0);
        }
        if (more) loadV(kt + 4);                 // prefetch next V into dead vf
    }

    // ---- merge = pure sums (no max state)
    if (w > 0) {
        #pragma unroll
        for (int ht = 0; ht < 4; ht++)
            #pragma unroll
            for (int r = 0; r < 4; r++) oS[w - 1][lane][ht * 4 + r] = o[ht][r];
        oS[w - 1][lane][16] = l_run;
    }
    __syncthreads();
    if (w == 0) {
        #pragma unroll
        for (int j = 0; j < 3; j++) {
            #pragma unroll
            for (int ht = 0; ht < 4; ht++)
                #pragma unroll
                for (int r = 0; r < 4; r++) o[ht][r] += oS[j][lane][ht * 4 + r];
            l_run += oS[j][lane][16];
        }
        const float invl = (l_run > 0.f) ? (1.f / l_run) : 0.f;  // dead row -> 0
        #pragma unroll
        for (int ht = 0; ht < 4; ht++) {
            float4 ov = make_float4(o[ht][0] * invl, o[ht][1] * invl,
                                    o[ht][2] * invl, o[ht][3] * invl);
            *(float4*)(out + ((size_t)(b * T_) + qrow) * H_ + ht * 16 + quad * 4) = ov;
        }
    }
}

extern "C" void kernel_launch(void* const* d_in, const int* in_sizes, int n_in,
                              void* d_out, int out_size, void* d_ws, size_t ws_size,
                              hipStream_t stream) {
    const float* x    = (const float*)d_in[0];
    const float* mask = (const float*)d_in[1];
    const float* Wq   = (const float*)d_in[2];
    const float* Wk   = (const float*)d_in[3];
    const float* Wv   = (const float*)d_in[4];
    float* out = (float*)d_out;

    unsigned short* qf = (unsigned short*)d_ws;            // bf16 frag-packed [BT*H]
    unsigned short* kf = qf + (size_t)BT_ * H_;
    unsigned short* vf = kf + (size_t)BT_ * H_;
    unsigned short* wt = vf + (size_t)BT_ * H_;            // bf16 WTf[24][12][64][8]

    wprep<<<72, 256, 0, stream>>>(Wq, Wk, Wv, wt);
    qkv_kernel<<<BT_ / 16, 256, 0, stream>>>(x, wt, qf, kf, vf);
    attn_kernel<<<B_ * (T_ / 16), 256, 0, stream>>>(qf, kf, vf, mask, out);
}

// Round 3
// 114.831 us; speedup vs baseline: 1.0221x; 1.0078x over previous
//
#include <hip/hip_runtime.h>
#include <hip/hip_bf16.h>

#define B_ 8
#define T_ 2048
#define C_ 768
#define H_ 64
#define BT_ (B_*T_)

typedef __attribute__((ext_vector_type(8))) short bf16x8;
typedef __attribute__((ext_vector_type(4))) float f32x4;

__device__ __forceinline__ unsigned short f2bf(float x) {
    __hip_bfloat16 h = __float2bfloat16(x);   // RNE
    return __builtin_bit_cast(unsigned short, h);
}

__device__ __forceinline__ bf16x8 cvt8(float4 a, float4 b) {
    bf16x8 r;
    r[0] = (short)f2bf(a.x); r[1] = (short)f2bf(a.y);
    r[2] = (short)f2bf(a.z); r[3] = (short)f2bf(a.w);
    r[4] = (short)f2bf(b.x); r[5] = (short)f2bf(b.y);
    r[6] = (short)f2bf(b.z); r[7] = (short)f2bf(b.w);
    return r;
}

// ------------- W prep (coalesced): block = (m, gc); LDS transpose ---------------
__global__ __launch_bounds__(256) void wprep(
    const float* __restrict__ Wq, const float* __restrict__ Wk,
    const float* __restrict__ Wv, unsigned short* __restrict__ WTf)
{
    __shared__ float tile[32][68];
    const int bid = blockIdx.x;              // 72 = 3 m * 24 gc
    const int m = bid / 24, gc = bid % 24;
    const float* __restrict__ W = (m == 0) ? Wq : (m == 1) ? Wk : Wv;
    const int t = threadIdx.x;
    {
        const int r = t >> 3, c0 = (t & 7) * 8;
        float4 a = *(const float4*)(W + (size_t)(gc * 32 + r) * H_ + c0);
        float4 b = *(const float4*)(W + (size_t)(gc * 32 + r) * H_ + c0 + 4);
        *(float4*)&tile[r][c0]     = a;
        *(float4*)&tile[r][c0 + 4] = b;
    }
    __syncthreads();
    const int fl = t >> 6, lane = t & 63;
    const int q16 = lane & 15, quad = lane >> 4;
    const int f = m * 4 + fl;
    ushort4 u0, u1;
    u0.x = f2bf(tile[quad * 8 + 0][fl * 16 + q16]);
    u0.y = f2bf(tile[quad * 8 + 1][fl * 16 + q16]);
    u0.z = f2bf(tile[quad * 8 + 2][fl * 16 + q16]);
    u0.w = f2bf(tile[quad * 8 + 3][fl * 16 + q16]);
    u1.x = f2bf(tile[quad * 8 + 4][fl * 16 + q16]);
    u1.y = f2bf(tile[quad * 8 + 5][fl * 16 + q16]);
    u1.z = f2bf(tile[quad * 8 + 6][fl * 16 + q16]);
    u1.w = f2bf(tile[quad * 8 + 7][fl * 16 + q16]);
    unsigned short* __restrict__ dst = WTf + ((size_t)(gc * 12 + f) * 64 + lane) * 8;
    *(ushort4*)(dst)     = u0;
    *(ushort4*)(dst + 4) = u1;
}

// ------------- QKV via MFMA: 16 tokens/block, intra-block N-split, NO merge -----
// R14 config (best measured; untouched since — isolate the attn variable).
__global__ __launch_bounds__(256) void qkv_kernel(
    const float* __restrict__ x, const unsigned short* __restrict__ WTf,
    unsigned short* __restrict__ qF, unsigned short* __restrict__ kF,
    unsigned short* __restrict__ vF)
{
    __shared__ __align__(16) unsigned short xS[16 * 772];   // 24.7 KB, padded rows
    const int tid  = threadIdx.x;
    const int w    = tid >> 6;               // f-set 0..3
    const int lane = tid & 63;
    const int q16  = lane & 15, quad = lane >> 4;
    const int rowBase = blockIdx.x << 4;

    // ---- stage x: thread t = (row t>>4, l=t&15); 6 x 32B contiguous per thread
    {
        const int r = tid >> 4, l = tid & 15;
        const float* __restrict__ xrow = x + (size_t)(rowBase + r) * C_;
        #pragma unroll
        for (int i = 0; i < 6; i++) {
            const int j = i * 16 + l;        // 32B granule 0..95
            float4 a = *(const float4*)(xrow + j * 8);
            float4 b = *(const float4*)(xrow + j * 8 + 4);
            *(bf16x8*)&xS[(size_t)r * 772 + j * 8] = cvt8(a, b);
        }
    }
    __syncthreads();                          // the only barrier

    const int f0 = w * 3;
    const unsigned short* __restrict__ xrowS = xS + q16 * 772 + quad * 8;
    f32x4 acc[3] = {};
    #pragma unroll
    for (int c = 0; c < 24; c++) {
        const unsigned short* __restrict__ wpc =
            WTf + ((size_t)(c * 12 + f0)) * 512 + lane * 8;
        bf16x8 xf = *(const bf16x8*)(xrowS + c * 32);   // ds_read_b128, <=2-way
        bf16x8 w0 = *(const bf16x8*)(wpc);
        bf16x8 w1 = *(const bf16x8*)(wpc + 512);
        bf16x8 w2 = *(const bf16x8*)(wpc + 1024);
        acc[0] = __builtin_amdgcn_mfma_f32_16x16x32_bf16(w0, xf, acc[0], 0, 0, 0);
        acc[1] = __builtin_amdgcn_mfma_f32_16x16x32_bf16(w1, xf, acc[1], 0, 0, 0);
        acc[2] = __builtin_amdgcn_mfma_f32_16x16x32_bf16(w2, xf, acc[2], 0, 0, 0);
    }

    // ---- fragment-packed epilogue (R11 mapping), run by ALL waves in parallel
    const size_t gt = (size_t)(rowBase >> 4);
    #pragma unroll
    for (int j = 0; j < 3; j++) {
        const int f = f0 + j;                // wave-uniform
        if (f < 8) {
            ushort4 u;
            u.x = f2bf(acc[j][0]); u.y = f2bf(acc[j][1]);
            u.z = f2bf(acc[j][2]); u.w = f2bf(acc[j][3]);
            const int n4 = f & 3;
            const int qp = (2 * n4 + (quad >> 1)) & 3;
            const int j0 = (quad & 1) * 4;
            unsigned short* __restrict__ dst = (f < 4) ? qF : kF;
            *(ushort4*)(dst + ((gt * 2 + (n4 >> 1)) * 64 + q16 + 16 * qp) * 8 + j0) = u;
        } else {
            const size_t g32 = gt >> 1;
            const int qv = ((int)gt & 1) * 2 + (q16 >> 3);
            const int jv = q16 & 7;
            #pragma unroll
            for (int r = 0; r < 4; r++)
                vF[((g32 * 4 + (f - 8)) * 64 + quad * 4 + r + 16 * qv) * 8 + jv] =
                    f2bf(acc[j][r]);
        }
    }
}

// ------------- MFMA flash attention: 4-wave k-split, no-max softmax -------------
// R18: cut softmax VALU issue (~400 -> ~240 cy/iter). attn is VALU-issue-bound
// (R17's latency-prefetch was flat):
//  (1) raw __builtin_amdgcn_exp2f (v_exp_f32; exp2(-inf)=0) — drops the OCML
//      wrapper's denorm-fixup (~3 insts x 16/iter).
//  (2) drop the per-element sv==0 -> -inf check (16 cmp + 16 cndmask per iter).
//      The real case (mask row == 0 -> whole row -inf -> NaN-cleanup -> 0) is
//      handled EXACTLY by gating invl on mrow != 0 at the end; the only
//      divergence vs reference is an exactly-zero f32 dot with mask=1
//      (measure-zero).
//  (3) defer the l-reduction: l_run accumulates per-lane partials (sum is
//      linear); the 2 __shfl_xor run once after the loop, not per iteration.
//  Kept from R17: heavy-first LPT map, diagonal-only causal mask, tree psum,
//  rotated K/V prefetch (free).
__global__ __launch_bounds__(256) void attn_kernel(
    const unsigned short* __restrict__ qF, const unsigned short* __restrict__ kF,
    const unsigned short* __restrict__ vF, const float* __restrict__ mask,
    float* __restrict__ out)
{
    __shared__ __align__(16) unsigned short pS[4][16][88];  // wave-private P tiles
    __shared__ float oS[3][64][17];          // o[16] + l in slot 16; stride 17 odd

    const int tid  = threadIdx.x;
    const int w    = tid >> 6;
    const int lane = tid & 63;
    const int q16  = lane & 15;
    const int quad = lane >> 4;
    const int bid  = blockIdx.x;
    const int b    = bid & 7;                    // batches interleaved (XCD affinity)
    const int qt   = 127 - (bid >> 3);           // heavy q-tiles first (LPT)
    const int qrow = (qt << 4) + q16;

    const size_t qbase = ((size_t)(b * 128 + qt) * 2) * 512 + lane * 8;
    bf16x8 qf0 = *(const bf16x8*)(qF + qbase);
    bf16x8 qf1 = *(const bf16x8*)(qF + qbase + 512);
    // fold 1/sqrt(64) and log2(e): softmax runs in base-2 domain
    const float mrow  = mask[b * T_ + qrow];
    const float maskv = mrow * 0.125f * 1.44269504f;

    f32x4 o[4] = {};
    float l_run = 0.f;

    const int niter = ((qt << 4) + 16 + 63) >> 6;   // 64-wide k tiles
    const int dt    = niter - 1;                    // diagonal tile index

    bf16x8 kf[8], vf[8];
    auto loadK = [&](int kt_) {
        #pragma unroll
        for (int sub = 0; sub < 4; sub++) {
            const unsigned short* kp = kF + ((size_t)(b * 128 + kt_ * 4 + sub) * 2) * 512 + lane * 8;
            kf[2 * sub]     = *(const bf16x8*)(kp);
            kf[2 * sub + 1] = *(const bf16x8*)(kp + 512);
        }
    };
    auto loadV = [&](int kt_) {
        #pragma unroll
        for (int ht = 0; ht < 4; ht++) {
            const unsigned short* vp = vF + ((size_t)(b * 64 + kt_ * 2) * 4 + ht) * 512 + lane * 8;
            vf[2 * ht]     = *(const bf16x8*)(vp);
            vf[2 * ht + 1] = *(const bf16x8*)(vp + 4 * 512);
        }
    };

    if (w < niter) { loadK(w); loadV(w); }       // prologue (wave-uniform guard)

    for (int kt = w; kt < niter; kt += 4) {
        const int kbase = kt << 6;
        const bool more = (kt + 4 < niter);      // wave-uniform

        // ---- S^T = K.Q^T : D[k_local][q]  (kf dies here)
        f32x4 sa[4] = {};
        #pragma unroll
        for (int sub = 0; sub < 4; sub++) {
            sa[sub] = __builtin_amdgcn_mfma_f32_16x16x32_bf16(kf[2 * sub],     qf0, sa[sub], 0, 0, 0);
            sa[sub] = __builtin_amdgcn_mfma_f32_16x16x32_bf16(kf[2 * sub + 1], qf1, sa[sub], 0, 0, 0);
        }
        if (more) loadK(kt + 4);                 // prefetch next K into dead kf

        // ---- unnormalized softmax: p = exp2(s); mask==0 rows fixed in epilogue
        float p[16];
        if (kt != dt) {
            // interior tile: kidx <= qrow guaranteed, no causal compare needed
            #pragma unroll
            for (int e = 0; e < 16; e++)
                p[e] = __builtin_amdgcn_exp2f(sa[e >> 2][e & 3] * maskv);
        } else {
            // diagonal tile: causal mask path
            #pragma unroll
            for (int sub = 0; sub < 4; sub++)
                #pragma unroll
                for (int r = 0; r < 4; r++) {
                    int kidx = kbase + sub * 16 + quad * 4 + r;
                    float sv = sa[sub][r] * maskv;
                    sv = (kidx > qrow) ? -__builtin_inff() : sv;
                    p[sub * 4 + r] = __builtin_amdgcn_exp2f(sv);
                }
        }
        float psum = (((p[0] + p[1]) + (p[2] + p[3])) + ((p[4] + p[5]) + (p[6] + p[7])))
                   + (((p[8] + p[9]) + (p[10] + p[11])) + ((p[12] + p[13]) + (p[14] + p[15])));
        l_run += psum;                           // cross-lane reduce deferred

        // ---- P^T -> wave-private LDS as P[q][k] bf16 (intra-wave: no barrier)
        #pragma unroll
        for (int sub = 0; sub < 4; sub++) {
            unsigned int lo = (unsigned int)f2bf(p[sub * 4 + 0]) | ((unsigned int)f2bf(p[sub * 4 + 1]) << 16);
            unsigned int hi = (unsigned int)f2bf(p[sub * 4 + 2]) | ((unsigned int)f2bf(p[sub * 4 + 3]) << 16);
            *(uint2*)&pS[w][q16][sub * 16 + quad * 4] = make_uint2(lo, hi);
        }
        bf16x8 pf0 = *(const bf16x8*)&pS[w][q16][quad * 8];
        bf16x8 pf1 = *(const bf16x8*)&pS[w][q16][32 + quad * 8];

        // ---- O^T += V^T.P^T  (vf dies here)
        #pragma unroll
        for (int ht = 0; ht < 4; ht++) {
            o[ht] = __builtin_amdgcn_mfma_f32_16x16x32_bf16(vf[2 * ht],     pf0, o[ht], 0, 0, 0);
            o[ht] = __builtin_amdgcn_mfma_f32_16x16x32_bf16(vf[2 * ht + 1], pf1, o[ht], 0, 0, 0);
        }
        if (more) loadV(kt + 4);                 // prefetch next V into dead vf
    }

    // deferred cross-lane l reduction (k spans the quad dimension)
    l_run += __shfl_xor(l_run, 16);
    l_run += __shfl_xor(l_run, 32);

    // ---- merge = pure sums (no max state)
    if (w > 0) {
        #pragma unroll
        for (int ht = 0; ht < 4; ht++)
            #pragma unroll
            for (int r = 0; r < 4; r++) oS[w - 1][lane][ht * 4 + r] = o[ht][r];
        oS[w - 1][lane][16] = l_run;
    }
    __syncthreads();
    if (w == 0) {
        #pragma unroll
        for (int j = 0; j < 3; j++) {
            #pragma unroll
            for (int ht = 0; ht < 4; ht++)
                #pragma unroll
                for (int r = 0; r < 4; r++) o[ht][r] += oS[j][lane][ht * 4 + r];
            l_run += oS[j][lane][16];
        }
        // mrow == 0 -> whole row masked (-inf) -> softmax NaN -> cleaned to 0
        const float invl = (mrow != 0.f && l_run > 0.f) ? (1.f / l_run) : 0.f;
        #pragma unroll
        for (int ht = 0; ht < 4; ht++) {
            float4 ov = make_float4(o[ht][0] * invl, o[ht][1] * invl,
                                    o[ht][2] * invl, o[ht][3] * invl);
            *(float4*)(out + ((size_t)(b * T_) + qrow) * H_ + ht * 16 + quad * 4) = ov;
        }
    }
}

extern "C" void kernel_launch(void* const* d_in, const int* in_sizes, int n_in,
                              void* d_out, int out_size, void* d_ws, size_t ws_size,
                              hipStream_t stream) {
    const float* x    = (const float*)d_in[0];
    const float* mask = (const float*)d_in[1];
    const float* Wq   = (const float*)d_in[2];
    const float* Wk   = (const float*)d_in[3];
    const float* Wv   = (const float*)d_in[4];
    float* out = (float*)d_out;

    unsigned short* qf = (unsigned short*)d_ws;            // bf16 frag-packed [BT*H]
    unsigned short* kf = qf + (size_t)BT_ * H_;
    unsigned short* vf = kf + (size_t)BT_ * H_;
    unsigned short* wt = vf + (size_t)BT_ * H_;            // bf16 WTf[24][12][64][8]

    wprep<<<72, 256, 0, stream>>>(Wq, Wk, Wv, wt);
    qkv_kernel<<<BT_ / 16, 256, 0, stream>>>(x, wt, qf, kf, vf);
    attn_kernel<<<B_ * (T_ / 16), 256, 0, stream>>>(qf, kf, vf, mask, out);
}